// Round 10
// baseline (384.594 us; speedup 1.0000x reference)
//
#include <hip/hip_runtime.h>

typedef __bf16 bf16;
typedef __attribute__((ext_vector_type(8))) __bf16 bf16x8;
typedef __attribute__((ext_vector_type(4))) __bf16 bf16x4;
typedef __attribute__((ext_vector_type(4))) short short4_t;
typedef __attribute__((ext_vector_type(4))) float floatx4;

typedef const void __attribute__((address_space(1)))* gas1p;
typedef void __attribute__((address_space(3)))* las3p;

#define LOG2E 1.44269504088896340736f

static constexpr int D_MODEL = 1024;
static constexpr int N_HEADS = 16;
static constexpr int HDIM    = 64;
static constexpr int BSZ     = 8;
static constexpr int SEQ     = 1024;
static constexpr int ROWS    = BSZ * SEQ;   // 8192
static constexpr int FF_IN   = 1088;        // 17*64
static constexpr int FF_HID  = 2048;
static constexpr int QKV_LD  = 3072;        // q|k|v row stride in qkv buffer

__device__ __forceinline__ floatx4 mfma_bf16(bf16x8 a, bf16x8 b, floatx4 c) {
  return __builtin_amdgcn_mfma_f32_16x16x32_bf16(a, b, c, 0, 0, 0);
}

__device__ __forceinline__ floatx4 mfma16(bf16x4 a, bf16x4 b, floatx4 c) {
#if __has_builtin(__builtin_amdgcn_mfma_f32_16x16x16_bf16)
  return __builtin_amdgcn_mfma_f32_16x16x16_bf16(a, b, c, 0, 0, 0);
#else
  return __builtin_amdgcn_mfma_f32_16x16x16bf16_1k(
      __builtin_bit_cast(short4_t, a), __builtin_bit_cast(short4_t, b), c, 0, 0, 0);
#endif
}

__device__ __forceinline__ float fast_exp2(float x) {
#if __has_builtin(__builtin_amdgcn_exp2f)
  return __builtin_amdgcn_exp2f(x);   // raw v_exp_f32, no libm guards
#else
  return exp2f(x);
#endif
}

__device__ __forceinline__ float flex_load(const void* src, size_t idx, int isbf) {
  return isbf ? (float)((const bf16*)src)[idx] : ((const float*)src)[idx];
}

// ---------------- fused prep: x->bf16 | biases | weight transposes ----------------
struct TransJobs {
  const void* src[6];
  bf16* dst[6];
  int R[6], C[6];
  int tiles_x[6];
  int tile_base[7];
  float scale[6];
};

static constexpr int NBX = (ROWS * D_MODEL) / 2048;   // 4096 blocks, 8 elem/thr
static constexpr int NBB = 25;                         // bias blocks

__global__ __launch_bounds__(256)
void prep_all_kernel(const void* __restrict__ xsrc, bf16* __restrict__ xdst,
                     const void* bq, const void* bk, const void* bv,
                     const void* bin, const void* b1, const void* b2,
                     float* __restrict__ biasf, TransJobs J,
                     int* __restrict__ flagOut) {
  __shared__ float tile[32][33];
  __shared__ int cnt;
  // ---- local dtype detect (1 sample/thread, same indices every block) ----
  if (threadIdx.x == 0) cnt = 0;
  __syncthreads();
  {
    const unsigned v = ((const unsigned*)xsrc)[(size_t)threadIdx.x * 997 + 13];
    const unsigned bb = (v >> 8) & 0x7F;
    if (bb >= 0x3B && bb <= 0x41) atomicAdd(&cnt, 1);
  }
  __syncthreads();
  const int isbf = (cnt > 128) ? 1 : 0;
  const int bid = blockIdx.x;
  if (bid == NBX && threadIdx.x == 0) *flagOut = isbf;

  if (bid < NBX) {                       // ---- x -> bf16 ----
    const size_t i = ((size_t)bid * 256 + threadIdx.x) * 8;
    bf16x8 o;
    if (isbf) {
      o = *reinterpret_cast<const bf16x8*>((const bf16*)xsrc + i);
    } else {
      const float4 f0 = *reinterpret_cast<const float4*>((const float*)xsrc + i);
      const float4 f1 = *reinterpret_cast<const float4*>((const float*)xsrc + i + 4);
      o[0] = (bf16)f0.x; o[1] = (bf16)f0.y; o[2] = (bf16)f0.z; o[3] = (bf16)f0.w;
      o[4] = (bf16)f1.x; o[5] = (bf16)f1.y; o[6] = (bf16)f1.z; o[7] = (bf16)f1.w;
    }
    *reinterpret_cast<bf16x8*>(xdst + i) = o;
    return;
  }
  if (bid < NBX + NBB) {                 // ---- biases ----
    const int i = (bid - NBX) * 256 + threadIdx.x;
    if (i < 1024)      biasf[i] = flex_load(bq, i, isbf) * (0.125f * LOG2E);
    else if (i < 2048) biasf[i] = flex_load(bk, i - 1024, isbf);
    else if (i < 3072) biasf[i] = flex_load(bv, i - 2048, isbf);
    else if (i < 3136) biasf[i] = flex_load(bin, i - 3072, isbf);
    else if (i < 5184) biasf[i] = flex_load(b1, i - 3136, isbf);
    else if (i < 6208) biasf[i] = flex_load(b2, i - 5184, isbf);
    return;
  }
  // ---- weight transposes ----
  const int tb = bid - (NBX + NBB);
  int j = 0;
#pragma unroll
  for (int t = 1; t < 6; t++) j += (tb >= J.tile_base[t]) ? 1 : 0;
  const int t = tb - J.tile_base[j];
  const int c0 = (t % J.tiles_x[j]) * 32, r0 = (t / J.tiles_x[j]) * 32;
  const void* src = J.src[j];
  bf16* dst = J.dst[j];
  const int R = J.R[j], C = J.C[j];
  const float scale = J.scale[j];
  const int tx = threadIdx.x & 31, ty = threadIdx.x >> 5;
  for (int i = ty; i < 32; i += 8)
    tile[i][tx] = flex_load(src, (size_t)(r0 + i) * C + (c0 + tx), isbf);
  __syncthreads();
  for (int i = ty; i < 32; i += 8)
    dst[(size_t)(c0 + i) * R + (r0 + tx)] = (bf16)(tile[tx][i] * scale);
}

// ---------------- pipelined QKV GEMM: BM=256 BN=128 BK=64, 512 thr ----------------
// Round-10: corrected T3/T4 pipeline (R2's failure dissected per m196: it
// staged in a serial barrier-fenced slot with no phase interleave). Here:
//  * 3-buffer LDS rotation (144 KB, 1 block/CU): stage(T(t+2)) issued at the
//    TOP of step t into buf[(t+2)%3] (freed at the barrier ending step t-1) —
//    loads overlap the whole step's ds_read+MFMA, ~2 steps of slack.
//  * ONE raw s_barrier per K-step (NOT __syncthreads — that re-inserts the
//    vmcnt(0) drain). Counted vmcnt(6) before it: outstanding = T(t+1) 6 +
//    T(t+2) 6 loads; waiting to 6 proves this wave's T(t+1) landed; barrier
//    extends that to all waves. Never drains to 0 until the tail (T4).
//  * kk-phase split: 2x {8 ds_read_b128 -> setprio(1) 16 MFMA setprio(0)} (T5).
// Fragment layout + V_TRANS + dual-output epilogue copied verbatim from the
// verified 128^2 kernel (per-wave 64x64 identical; wm now spans 0..3).
__global__ __launch_bounds__(512)
void gemm_qkv_pipe(const bf16* __restrict__ A, const bf16* __restrict__ BT,
                   const float* __restrict__ bias, bf16* __restrict__ Cq,
                   bf16* __restrict__ C2, bf16* __restrict__ vt_out) {
  constexpr int BM = 256, BN = 128, BK = 64, KDIM = 1024, NT = KDIM / BK;
  __shared__ __align__(16) bf16 As[3][BM * BK];   // 3 x 32 KB
  __shared__ __align__(16) bf16 Bs[3][BN * BK];   // 3 x 16 KB  -> 144 KB
  const int tid = threadIdx.x;
  const int wave = tid >> 6, lane = tid & 63;
  const int quad = lane >> 4, lo = lane & 15;
  const int wm = wave >> 1, wn = wave & 1;        // 4 M-waves x 2 N-waves

  // XCD-chunk + supertile swizzle: nwg = 800 = 32 x-tiles(M) * 25 y-tiles(N)
  const int bid = blockIdx.x;
  const int sid = (bid & 7) * 100 + (bid >> 3);
  const int g = sid / 200, r2 = sid - g * 200;
  const int m0 = (g * 8 + (r2 & 7)) * BM;
  const int n0 = (r2 >> 3) * BN;

  auto stage = [&](int t, int cb) {
    const size_t kb = (size_t)t * BK;
#pragma unroll
    for (int u = 0; u < 4; u++) {               // A: 256x64 = 4 loads/thread
      const int c = u * 512 + tid;
      const int row = c >> 3;
      const int gcol = (c & 7) ^ (row & 7);
      __builtin_amdgcn_global_load_lds(
          (gas1p)(A + (size_t)(m0 + row) * KDIM + kb + gcol * 8),
          (las3p)(&As[cb][c * 8]), 16, 0, 0);
    }
#pragma unroll
    for (int u = 0; u < 2; u++) {               // B: 128x64 = 2 loads/thread
      const int c = u * 512 + tid;
      const int row = c >> 3;
      const int gcol = (c & 7) ^ (row & 7);
      __builtin_amdgcn_global_load_lds(
          (gas1p)(BT + (size_t)(n0 + row) * KDIM + kb + gcol * 8),
          (las3p)(&Bs[cb][c * 8]), 16, 0, 0);
    }
  };

  floatx4 acc[4][4];
#pragma unroll
  for (int i = 0; i < 4; i++)
#pragma unroll
    for (int j = 0; j < 4; j++) acc[i][j] = floatx4{0.f, 0.f, 0.f, 0.f};

  // prologue: tiles 0,1 in flight; vmcnt(6) proves tile 0 landed
  stage(0, 0);
  stage(1, 1);
  asm volatile("s_waitcnt vmcnt(6)" ::: "memory");
  asm volatile("s_barrier" ::: "memory");

  for (int t = 0; t < NT; ++t) {
    const int cb = t % 3;
    if (t + 2 < NT) stage(t + 2, (t + 2) % 3);   // overlaps this whole step
    const bf16* Asc = As[cb];
    const bf16* Bsc = Bs[cb];
#pragma unroll
    for (int kk = 0; kk < 2; kk++) {
      bf16x8 af[4], bfr[4];
#pragma unroll
      for (int tr = 0; tr < 4; tr++) {
        const int row = wm * 64 + tr * 16 + lo;
        const int cc = (kk * 4 + quad) ^ (lo & 7);
        af[tr] = *reinterpret_cast<const bf16x8*>(Asc + row * BK + cc * 8);
      }
#pragma unroll
      for (int tc = 0; tc < 4; tc++) {
        const int row = wn * 64 + tc * 16 + lo;
        const int cc = (kk * 4 + quad) ^ (lo & 7);
        bfr[tc] = *reinterpret_cast<const bf16x8*>(Bsc + row * BK + cc * 8);
      }
      __builtin_amdgcn_s_setprio(1);
#pragma unroll
      for (int tr = 0; tr < 4; tr++)
#pragma unroll
        for (int tc = 0; tc < 4; tc++)
          acc[tr][tc] = mfma_bf16(af[tr], bfr[tc], acc[tr][tc]);
      __builtin_amdgcn_s_setprio(0);
    }
    // counted wait: need T(t+1) resident; T(t+2) (6 loads) may stay in flight
    if (t + 2 < NT)      asm volatile("s_waitcnt vmcnt(6)" ::: "memory");
    else if (t + 1 < NT) asm volatile("s_waitcnt vmcnt(0)" ::: "memory");
    asm volatile("s_barrier" ::: "memory");   // also fences epilogue LDS reuse
  }

  // ---- V-transpose epilogue (block-uniform branch) ----
  if (n0 >= 2048 && n0 < 3072) {
    const int h = ((n0 - 2048) >> 6) + wn;
    const int b = m0 >> 10;                    // 256 | 1024 -> uniform
    const int ibase = (m0 & 1023) + wm * 64;
    bf16* L = &As[0][0] + wave * 4096;         // private 64x64 slab (8 KB)
#pragma unroll
    for (int tc = 0; tc < 4; tc++) {
      const int d = tc * 16 + lo;
      const float bval = bias[n0 + wn * 64 + d];
#pragma unroll
      for (int tr = 0; tr < 4; tr++) {
        const int iin = tr * 16 + quad * 4;
        bf16x4 p;
#pragma unroll
        for (int rr = 0; rr < 4; rr++) p[rr] = (bf16)(acc[tr][tc][rr] + bval);
        *reinterpret_cast<bf16x4*>(L + d * 64 + (iin ^ ((d & 7) << 3))) = p;
      }
    }
    asm volatile("s_waitcnt lgkmcnt(0)" ::: "memory");
    bf16* dst = vt_out + (size_t)(b * 16 + h) * (HDIM * SEQ) + ibase;
#pragma unroll
    for (int w8 = 0; w8 < 8; w8++) {
      const int dp = w8 * 8 + (lane >> 3);
      const int ip = (lane & 7) * 8;
      const bf16x8 v = *reinterpret_cast<const bf16x8*>(
          L + dp * 64 + (ip ^ ((dp & 7) << 3)));
      *reinterpret_cast<bf16x8*>(dst + (size_t)dp * SEQ + ip) = v;
    }
    return;
  }

  // ---- q|k columns -> Cq (ldc QKV_LD); in-proj tail -> C2 ----
#pragma unroll
  for (int tc = 0; tc < 4; tc++) {
    const int col = n0 + wn * 64 + tc * 16 + lo;
    const float bval = bias[col];
    if (col < 3072) {
#pragma unroll
      for (int tr = 0; tr < 4; tr++) {
        const int rbase = m0 + wm * 64 + tr * 16 + quad * 4;
#pragma unroll
        for (int rr = 0; rr < 4; rr++)
          Cq[(size_t)(rbase + rr) * QKV_LD + col] = (bf16)(acc[tr][tc][rr] + bval);
      }
    } else if (col < 3136) {
#pragma unroll
      for (int tr = 0; tr < 4; tr++) {
        const int rbase = m0 + wm * 64 + tr * 16 + quad * 4;
#pragma unroll
        for (int rr = 0; rr < 4; rr++)
          C2[(size_t)(rbase + rr) * FF_IN + (col - 3072)] =
              (bf16)(acc[tr][tc][rr] + bval);
      }
    }
  }
}

// ---------------- GEMM: C[M,N] = A[M,K] @ BT[N,K]^T + bias ----------------
// Round-4 verified structure (128x128, BK=64, 256 thr, 2-barrier, 32 KB LDS,
// ~5 blocks/CU). Used for FF1/FF2 (plain 2-D grids, gy=0).
template <int BN, bool DO_RELU, bool OUT_FLEX, bool V_TRANS>
__global__ __launch_bounds__(256)
void gemm_bt(const bf16* __restrict__ A, const bf16* __restrict__ BT,
             const float* __restrict__ bias,
             void* __restrict__ Cv, int N, int K, int ldc,
             bf16* __restrict__ C2, int ldc2, int nsplit, int nvalid,
             int gy, bf16* __restrict__ vt_out,
             const int* __restrict__ flag) {
  constexpr int BM = 128, BK = 64;
  constexpr int TCN = BN / 32;
  constexpr int ACH = (BM * BK) / (256 * 8);   // 4
  constexpr int BCH = (BN * BK) / (256 * 8);   // 4 (BN=128)
  __shared__ __align__(16) char smem_raw[(BM * BK + BN * BK) * 2];  // 32 KB
  bf16* As = (bf16*)smem_raw;
  bf16* Bs = As + BM * BK;
  const int tid = threadIdx.x;
  const int wave = tid >> 6, lane = tid & 63;
  const int quad = lane >> 4, lo = lane & 15;
  const int wm = wave >> 1, wn = wave & 1;

  int m0, n0;
  if (gy == 0) {             // plain 2-D grid
    m0 = blockIdx.x * BM;
    n0 = blockIdx.y * BN;
  } else {                   // XCD-chunk + supertile swizzle (1-D grid)
    const int nwg = gridDim.x;
    const int bid = blockIdx.x;
    const int sid = (bid & 7) * (nwg >> 3) + (bid >> 3);
    const int P = gy << 3;
    const int g = sid / P, r2 = sid - g * P;
    m0 = (g * 8 + (r2 & 7)) * BM;
    n0 = (r2 >> 3) * BN;
  }

  floatx4 acc[4][TCN];
#pragma unroll
  for (int i = 0; i < 4; i++)
#pragma unroll
    for (int j = 0; j < TCN; j++) acc[i][j] = floatx4{0.f, 0.f, 0.f, 0.f};

  for (int kb = 0; kb < K; kb += BK) {
#pragma unroll
    for (int u = 0; u < ACH; u++) {
      const int c = u * 256 + tid;
      const int row = c >> 3, col = c & 7;
      const int gcol = col ^ (row & 7);
      const bf16* gp = A + (size_t)(m0 + row) * K + kb + gcol * 8;
      __builtin_amdgcn_global_load_lds((gas1p)gp, (las3p)(As + c * 8), 16, 0, 0);
    }
#pragma unroll
    for (int u = 0; u < BCH; u++) {
      const int c = u * 256 + tid;
      const int row = c >> 3, col = c & 7;
      const int gcol = col ^ (row & 7);
      const bf16* gp = BT + (size_t)(n0 + row) * K + kb + gcol * 8;
      __builtin_amdgcn_global_load_lds((gas1p)gp, (las3p)(Bs + c * 8), 16, 0, 0);
    }
    __syncthreads();
#pragma unroll
    for (int kk = 0; kk < 2; kk++) {
      bf16x8 af[4], bfr[TCN];
#pragma unroll
      for (int tr = 0; tr < 4; tr++) {
        const int row = wm * 64 + tr * 16 + lo;
        const int cc = (kk * 4 + quad) ^ (lo & 7);
        af[tr] = *reinterpret_cast<const bf16x8*>(As + row * BK + cc * 8);
      }
#pragma unroll
      for (int tc = 0; tc < TCN; tc++) {
        const int row = wn * (BN / 2) + tc * 16 + lo;
        const int cc = (kk * 4 + quad) ^ (lo & 7);
        bfr[tc] = *reinterpret_cast<const bf16x8*>(Bs + row * BK + cc * 8);
      }
#pragma unroll
      for (int tr = 0; tr < 4; tr++)
#pragma unroll
        for (int tc = 0; tc < TCN; tc++)
          acc[tr][tc] = mfma_bf16(af[tr], bfr[tc], acc[tr][tc]);
    }
    __syncthreads();
  }

  // ---- V-transpose epilogue (block-uniform branch) ----
  if (V_TRANS && n0 >= 2048 && n0 < 3072) {
    const int h = ((n0 - 2048) >> 6) + wn;
    const int b = m0 >> 10;
    const int ibase = (m0 & 1023) + wm * 64;
    bf16* L = ((bf16*)smem_raw) + wave * 4096;    // private 64x64 slab (8 KB)
#pragma unroll
    for (int tc = 0; tc < TCN; tc++) {
      const int d = tc * 16 + lo;
      const float bval = bias[n0 + wn * 64 + d];
#pragma unroll
      for (int tr = 0; tr < 4; tr++) {
        const int iin = tr * 16 + quad * 4;
        bf16x4 p;
#pragma unroll
        for (int rr = 0; rr < 4; rr++) p[rr] = (bf16)(acc[tr][tc][rr] + bval);
        *reinterpret_cast<bf16x4*>(L + d * 64 + (iin ^ ((d & 7) << 3))) = p;
      }
    }
    asm volatile("s_waitcnt lgkmcnt(0)" ::: "memory");
    bf16* dst = vt_out + (size_t)(b * 16 + h) * (HDIM * SEQ) + ibase;
#pragma unroll
    for (int w8 = 0; w8 < 8; w8++) {
      const int dp = w8 * 8 + (lane >> 3);
      const int ip = (lane & 7) * 8;
      const bf16x8 v = *reinterpret_cast<const bf16x8*>(
          L + dp * 64 + (ip ^ ((dp & 7) << 3)));
      *reinterpret_cast<bf16x8*>(dst + (size_t)dp * SEQ + ip) = v;
    }
    return;
  }

  const int isbf = OUT_FLEX ? *flag : 1;
#pragma unroll
  for (int tc = 0; tc < TCN; tc++) {
    const int col = n0 + wn * (BN / 2) + tc * 16 + lo;
    const float bval = bias[col];
    if (col < nsplit) {
#pragma unroll
      for (int tr = 0; tr < 4; tr++) {
        const int rbase = m0 + wm * 64 + tr * 16 + quad * 4;
#pragma unroll
        for (int rr = 0; rr < 4; rr++) {
          float v = acc[tr][tc][rr] + bval;
          if (DO_RELU) v = fmaxf(v, 0.f);
          const size_t idx = (size_t)(rbase + rr) * ldc + col;
          if (!OUT_FLEX || isbf) ((bf16*)Cv)[idx] = (bf16)v;
          else                   ((float*)Cv)[idx] = v;
        }
      }
    } else if (col < nvalid) {
#pragma unroll
      for (int tr = 0; tr < 4; tr++) {
        const int rbase = m0 + wm * 64 + tr * 16 + quad * 4;
#pragma unroll
        for (int rr = 0; rr < 4; rr++) {
          float v = acc[tr][tc][rr] + bval;
          if (DO_RELU) v = fmaxf(v, 0.f);
          C2[(size_t)(rbase + rr) * ldc2 + (col - nsplit)] = (bf16)v;
        }
      }
    }
  }
}

// ---------------- flash attention: S^T formulation + LDS staging ----------------
// i-block 64 rows, grid 2048 (R4 win); T14 async reg-staging (R9, neutral+).
__global__ __launch_bounds__(256)
void attn_kernel(const bf16* __restrict__ QKV, const bf16* __restrict__ Vt,
                 bf16* __restrict__ Cc) {
  __shared__ bf16 Ks[64 * 64];
  __shared__ bf16 Vs[64 * 64];
  const int bid = blockIdx.x;
  const int xcd = bid & 7, g = bid >> 3;
  const int ib = g & 15, bh = (g >> 4) * 8 + xcd;
  const int b = bh >> 4, h = bh & 15;
  const int i0 = ib * 64;
  const int tid = threadIdx.x, wave = tid >> 6, lane = tid & 63;
  const int quad = lane >> 4, lo = lane & 15;
  const int iw = i0 + wave * 16;
  const bf16* qptr = QKV + (size_t)b * SEQ * QKV_LD + h * HDIM;
  const bf16* kptr = QKV + (size_t)b * SEQ * QKV_LD + 1024 + h * HDIM;
  const bf16* vptr = Vt + (size_t)bh * HDIM * SEQ;

  // staging decomposition (loop-invariant)
  const int c0 = tid, c1 = 256 + tid;
  const int row0 = c0 >> 3, gcol0 = (c0 & 7) ^ (row0 & 7);
  const int row1 = c1 >> 3, gcol1 = (c1 & 7) ^ (row1 & 7);

  bf16x8 qf[2];
#pragma unroll
  for (int kf = 0; kf < 2; kf++)
    qf[kf] = *reinterpret_cast<const bf16x8*>(
        qptr + (size_t)(iw + lo) * QKV_LD + kf * 32 + quad * 8);

  floatx4 oacc[4];
  float lrow = 0.f;
#pragma unroll
  for (int dt = 0; dt < 4; dt++) oacc[dt] = floatx4{0.f, 0.f, 0.f, 0.f};

  // prologue: load tile 0 into registers
  bf16x8 kreg0 = *reinterpret_cast<const bf16x8*>(
      kptr + (size_t)row0 * QKV_LD + gcol0 * 8);
  bf16x8 kreg1 = *reinterpret_cast<const bf16x8*>(
      kptr + (size_t)row1 * QKV_LD + gcol1 * 8);
  bf16x8 vreg0 = *reinterpret_cast<const bf16x8*>(
      vptr + (size_t)row0 * SEQ + gcol0 * 8);
  bf16x8 vreg1 = *reinterpret_cast<const bf16x8*>(
      vptr + (size_t)row1 * SEQ + gcol1 * 8);

  for (int jb = 0; jb < SEQ / 64; jb++) {
    const int j0 = jb * 64;
    __syncthreads();   // all waves done reading previous tile
    *reinterpret_cast<bf16x8*>(Ks + c0 * 8) = kreg0;
    *reinterpret_cast<bf16x8*>(Ks + c1 * 8) = kreg1;
    *reinterpret_cast<bf16x8*>(Vs + c0 * 8) = vreg0;
    *reinterpret_cast<bf16x8*>(Vs + c1 * 8) = vreg1;
    __syncthreads();   // tile jb visible in LDS
    if (jb + 1 < SEQ / 64) {
      const int jn = j0 + 64;   // loads overlap the compute phase below
      kreg0 = *reinterpret_cast<const bf16x8*>(
          kptr + (size_t)(jn + row0) * QKV_LD + gcol0 * 8);
      kreg1 = *reinterpret_cast<const bf16x8*>(
          kptr + (size_t)(jn + row1) * QKV_LD + gcol1 * 8);
      vreg0 = *reinterpret_cast<const bf16x8*>(
          vptr + (size_t)row0 * SEQ + jn + gcol0 * 8);
      vreg1 = *reinterpret_cast<const bf16x8*>(
          vptr + (size_t)row1 * SEQ + jn + gcol1 * 8);
    }

    floatx4 sacc[4];
#pragma unroll
    for (int mt = 0; mt < 4; mt++) sacc[mt] = floatx4{0.f, 0.f, 0.f, 0.f};
    __builtin_amdgcn_s_setprio(1);
#pragma unroll
    for (int mt = 0; mt < 4; mt++) {
      const int r = mt * 16 + lo;
      const int cc0 = quad ^ (lo & 7);
      const int cc1 = (4 + quad) ^ (lo & 7);
      const bf16x8 k0 = *reinterpret_cast<const bf16x8*>(Ks + r * 64 + cc0 * 8);
      const bf16x8 k1 = *reinterpret_cast<const bf16x8*>(Ks + r * 64 + cc1 * 8);
      sacc[mt] = mfma_bf16(k0, qf[0], sacc[mt]);
      sacc[mt] = mfma_bf16(k1, qf[1], sacc[mt]);
    }
    __builtin_amdgcn_s_setprio(0);

    if (j0 == i0) {
      const int ig = iw + lo;
#pragma unroll
      for (int mt = 0; mt < 4; mt++)
#pragma unroll
        for (int r = 0; r < 4; r++)
          if (j0 + mt * 16 + quad * 4 + r == ig) sacc[mt][r] = -1e30f;
    }

    bf16x4 pfrag[4];
    {
      float s0 = 0.f, s1 = 0.f;
#pragma unroll
      for (int mt = 0; mt < 4; mt++) {
        bf16x4 pk;
#pragma unroll
        for (int r = 0; r < 4; r++) {
          const float p = fast_exp2(sacc[mt][r]);  // LOG2E folded into q scale
          if (mt & 1) s1 += p; else s0 += p;
          pk[r] = (bf16)p;
        }
        pfrag[mt] = pk;
      }
      float s = s0 + s1;
      s += __shfl_xor(s, 16);
      s += __shfl_xor(s, 32);
      lrow += s;
    }

    __builtin_amdgcn_s_setprio(1);
#pragma unroll
    for (int dt = 0; dt < 4; dt++) {
      const int r = dt * 16 + lo;
#pragma unroll
      for (int kt = 0; kt < 4; kt++) {
        const int gch = kt * 2 + (quad >> 1);
        const int cc = gch ^ (lo & 7);
        const bf16x4 vf = *reinterpret_cast<const bf16x4*>(
            Vs + r * 64 + cc * 8 + (quad & 1) * 4);
        oacc[dt] = mfma16(vf, pfrag[kt], oacc[dt]);
      }
    }
    __builtin_amdgcn_s_setprio(0);
  }

  {
    const int ig = iw + lo;
    const float inv = 1.0f / lrow;
    bf16* cb = Cc + ((size_t)b * SEQ + ig) * FF_IN + h * HDIM;
#pragma unroll
    for (int dt = 0; dt < 4; dt++) {
      bf16x4 o;
#pragma unroll
      for (int r = 0; r < 4; r++) o[r] = (bf16)(oacc[dt][r] * inv);
      *reinterpret_cast<bf16x4*>(cb + dt * 16 + quad * 4) = o;
    }
  }
}

// ---------------- launch ----------------
extern "C" void kernel_launch(void* const* d_in, const int* in_sizes, int n_in,
                              void* d_out, int out_size, void* d_ws, size_t ws_size,
                              hipStream_t stream) {
  (void)in_sizes; (void)n_in; (void)out_size; (void)ws_size;
  const void* x   = d_in[0];
  const void* Wq  = d_in[1];
  const void* bq  = d_in[2];
  const void* Wk  = d_in[3];
  const void* bk  = d_in[4];
  const void* Wv  = d_in[5];
  const void* bv  = d_in[6];
  const void* Win = d_in[7];
  const void* bin = d_in[8];
  const void* W1  = d_in[9];
  const void* b1  = d_in[10];
  const void* W2  = d_in[11];
  const void* b2  = d_in[12];

  size_t off = 0;
  char* wsb = (char*)d_ws;
  auto alloc = [&](size_t bytes) {
    void* p = (void*)(wsb + off);
    off += (bytes + 255) & ~(size_t)255;
    return p;
  };
  int*   flag  = (int*)alloc(4);
  bf16*  xbf   = (bf16*)alloc((size_t)ROWS * D_MODEL * 2);
  bf16*  WqkvT = (bf16*)alloc((size_t)3200 * 1024 * 2);  // q|k|v|in rows + pad
  bf16*  W1T   = (bf16*)alloc((size_t)FF_HID * FF_IN * 2);
  bf16*  W2T   = (bf16*)alloc((size_t)D_MODEL * FF_HID * 2);
  float* biasf = (float*)alloc(6208 * 4);   // qkv | bin | b1 | b2
  bf16*  qkv   = (bf16*)alloc((size_t)ROWS * QKV_LD * 2);
  bf16*  vtb   = (bf16*)alloc((size_t)ROWS * D_MODEL * 2);
  bf16*  cbuf  = (bf16*)alloc((size_t)ROWS * FF_IN * 2);
  bf16*  hbuf  = (bf16*)alloc((size_t)ROWS * FF_HID * 2);
  float* b1f   = biasf + 3136;
  float* b2f   = biasf + 5184;

  const dim3 blk(256);

  TransJobs J;
  J.src[0] = Wq;  J.dst[0] = WqkvT;                        J.R[0] = 1024; J.C[0] = 1024; J.scale[0] = 0.125f * LOG2E;
  J.src[1] = Wk;  J.dst[1] = WqkvT + (size_t)1024 * 1024;  J.R[1] = 1024; J.C[1] = 1024; J.scale[1] = 1.0f;
  J.src[2] = Wv;  J.dst[2] = WqkvT + (size_t)2048 * 1024;  J.R[2] = 1024; J.C[2] = 1024; J.scale[2] = 1.0f;
  J.src[3] = Win; J.dst[3] = WqkvT + (size_t)3072 * 1024;  J.R[3] = 1024; J.C[3] = 64;   J.scale[3] = 1.0f;
  J.src[4] = W1;  J.dst[4] = W1T;                          J.R[4] = 1088; J.C[4] = 2048; J.scale[4] = 1.0f;
  J.src[5] = W2;  J.dst[5] = W2T;                          J.R[5] = 2048; J.C[5] = 1024; J.scale[5] = 1.0f;
  int base = 0;
  for (int j = 0; j < 6; j++) {
    J.tiles_x[j] = J.C[j] / 32;
    J.tile_base[j] = base;
    base += (J.R[j] / 32) * (J.C[j] / 32);
  }
  J.tile_base[6] = base;

  // fused prep: x->bf16 (4096) | biases (25) | transposes (base); self-detects
  prep_all_kernel<<<dim3(NBX + NBB + base), blk, 0, stream>>>(
      x, xbf, bq, bk, bv, bin, b1, b2, biasf, J, flag);

  // pipelined QKV + in-proj projection: 1-D grid 800 = 32 M-tiles x 25 N-tiles
  // (XCD-chunk swizzled in-kernel). cols [0,2048) -> qkv (q|k),
  // [2048,3072) -> vtb TRANSPOSED, [3072,3136) -> cbuf tail, rest dropped.
  gemm_qkv_pipe<<<dim3(800), dim3(512), 0, stream>>>(
      xbf, WqkvT, biasf, qkv, cbuf + 1024, vtb);

  attn_kernel<<<dim3(2048), blk, 0, stream>>>(qkv, vtb, cbuf);

  // FFN: plain 2-D grids, BN=128 (round-4 verified config).
  gemm_bt<128, true, false, false><<<dim3(64, 16), blk, 0, stream>>>(
      cbuf, W1T, b1f, hbuf, FF_HID, FF_IN, FF_HID,
      nullptr, 0, FF_HID, FF_HID, 0, nullptr, nullptr);
  gemm_bt<128, false, true, false><<<dim3(64, 8), blk, 0, stream>>>(
      hbuf, W2T, b2f, d_out, D_MODEL, FF_HID, D_MODEL,
      nullptr, 0, D_MODEL, D_MODEL, 0, nullptr, flag);
}

// Round 11
// 375.375 us; speedup vs baseline: 1.0246x; 1.0246x over previous
//
#include <hip/hip_runtime.h>

typedef __bf16 bf16;
typedef __attribute__((ext_vector_type(8))) __bf16 bf16x8;
typedef __attribute__((ext_vector_type(4))) __bf16 bf16x4;
typedef __attribute__((ext_vector_type(4))) short short4_t;
typedef __attribute__((ext_vector_type(4))) float floatx4;

typedef const void __attribute__((address_space(1)))* gas1p;
typedef void __attribute__((address_space(3)))* las3p;

#define LOG2E 1.44269504088896340736f

static constexpr int D_MODEL = 1024;
static constexpr int N_HEADS = 16;
static constexpr int HDIM    = 64;
static constexpr int BSZ     = 8;
static constexpr int SEQ     = 1024;
static constexpr int ROWS    = BSZ * SEQ;   // 8192
static constexpr int FF_IN   = 1088;        // 17*64
static constexpr int FF_HID  = 2048;
static constexpr int QKV_LD  = 3072;        // q|k|v row stride in qkv buffer

__device__ __forceinline__ floatx4 mfma_bf16(bf16x8 a, bf16x8 b, floatx4 c) {
  return __builtin_amdgcn_mfma_f32_16x16x32_bf16(a, b, c, 0, 0, 0);
}

__device__ __forceinline__ floatx4 mfma16(bf16x4 a, bf16x4 b, floatx4 c) {
#if __has_builtin(__builtin_amdgcn_mfma_f32_16x16x16_bf16)
  return __builtin_amdgcn_mfma_f32_16x16x16_bf16(a, b, c, 0, 0, 0);
#else
  return __builtin_amdgcn_mfma_f32_16x16x16bf16_1k(
      __builtin_bit_cast(short4_t, a), __builtin_bit_cast(short4_t, b), c, 0, 0, 0);
#endif
}

__device__ __forceinline__ float fast_exp2(float x) {
#if __has_builtin(__builtin_amdgcn_exp2f)
  return __builtin_amdgcn_exp2f(x);   // raw v_exp_f32, no libm guards
#else
  return exp2f(x);
#endif
}

__device__ __forceinline__ float flex_load(const void* src, size_t idx, int isbf) {
  return isbf ? (float)((const bf16*)src)[idx] : ((const float*)src)[idx];
}

// ---------------- fused prep: x->bf16 | biases | weight transposes ----------------
struct TransJobs {
  const void* src[6];
  bf16* dst[6];
  int R[6], C[6];
  int tiles_x[6];
  int tile_base[7];
  float scale[6];
};

static constexpr int NBX = (ROWS * D_MODEL) / 2048;   // 4096 blocks, 8 elem/thr
static constexpr int NBB = 25;                         // bias blocks

__global__ __launch_bounds__(256)
void prep_all_kernel(const void* __restrict__ xsrc, bf16* __restrict__ xdst,
                     const void* bq, const void* bk, const void* bv,
                     const void* bin, const void* b1, const void* b2,
                     float* __restrict__ biasf, TransJobs J,
                     int* __restrict__ flagOut) {
  __shared__ float tile[32][33];
  __shared__ int cnt;
  // ---- local dtype detect (1 sample/thread, same indices every block) ----
  if (threadIdx.x == 0) cnt = 0;
  __syncthreads();
  {
    const unsigned v = ((const unsigned*)xsrc)[(size_t)threadIdx.x * 997 + 13];
    const unsigned bb = (v >> 8) & 0x7F;
    if (bb >= 0x3B && bb <= 0x41) atomicAdd(&cnt, 1);
  }
  __syncthreads();
  const int isbf = (cnt > 128) ? 1 : 0;
  const int bid = blockIdx.x;
  if (bid == NBX && threadIdx.x == 0) *flagOut = isbf;

  if (bid < NBX) {                       // ---- x -> bf16 ----
    const size_t i = ((size_t)bid * 256 + threadIdx.x) * 8;
    bf16x8 o;
    if (isbf) {
      o = *reinterpret_cast<const bf16x8*>((const bf16*)xsrc + i);
    } else {
      const float4 f0 = *reinterpret_cast<const float4*>((const float*)xsrc + i);
      const float4 f1 = *reinterpret_cast<const float4*>((const float*)xsrc + i + 4);
      o[0] = (bf16)f0.x; o[1] = (bf16)f0.y; o[2] = (bf16)f0.z; o[3] = (bf16)f0.w;
      o[4] = (bf16)f1.x; o[5] = (bf16)f1.y; o[6] = (bf16)f1.z; o[7] = (bf16)f1.w;
    }
    *reinterpret_cast<bf16x8*>(xdst + i) = o;
    return;
  }
  if (bid < NBX + NBB) {                 // ---- biases ----
    const int i = (bid - NBX) * 256 + threadIdx.x;
    if (i < 1024)      biasf[i] = flex_load(bq, i, isbf) * (0.125f * LOG2E);
    else if (i < 2048) biasf[i] = flex_load(bk, i - 1024, isbf);
    else if (i < 3072) biasf[i] = flex_load(bv, i - 2048, isbf);
    else if (i < 3136) biasf[i] = flex_load(bin, i - 3072, isbf);
    else if (i < 5184) biasf[i] = flex_load(b1, i - 3136, isbf);
    else if (i < 6208) biasf[i] = flex_load(b2, i - 5184, isbf);
    return;
  }
  // ---- weight transposes ----
  const int tb = bid - (NBX + NBB);
  int j = 0;
#pragma unroll
  for (int t = 1; t < 6; t++) j += (tb >= J.tile_base[t]) ? 1 : 0;
  const int t = tb - J.tile_base[j];
  const int c0 = (t % J.tiles_x[j]) * 32, r0 = (t / J.tiles_x[j]) * 32;
  const void* src = J.src[j];
  bf16* dst = J.dst[j];
  const int R = J.R[j], C = J.C[j];
  const float scale = J.scale[j];
  const int tx = threadIdx.x & 31, ty = threadIdx.x >> 5;
  for (int i = ty; i < 32; i += 8)
    tile[i][tx] = flex_load(src, (size_t)(r0 + i) * C + (c0 + tx), isbf);
  __syncthreads();
  for (int i = ty; i < 32; i += 8)
    dst[(size_t)(c0 + i) * R + (r0 + tx)] = (bf16)(tile[tx][i] * scale);
}

// ---------------- GEMM: C[M,N] = A[M,K] @ BT[N,K]^T + bias ----------------
// Verified 2-barrier structure (BK=64, 256 thr, XOR-swizzled global_load_lds
// staging, ~5 blocks/CU at BM=128). Round-10's 256-wide deep pipeline
// regressed AGAIN (101 us, VALUBusy 14%) -> definitively reverted; at K=1024
// inter-block TLP beats intra-block pipelining.
// Round-11: BM templated. FF2 uses BM=64 (grid 128x8=1024 blocks, 4-6/CU
// instead of 2/CU). BN stays 128 so N-panel count and A-traffic are
// UNCHANGED (R7's BN=64 mistake doubled A reads); the extra B re-reads hit
// the L2-resident 4 MB W2T. gy>0 -> XCD-chunk supertile swizzle (verified
// -22 us on QKV across rounds 6-9).
template <int BM, int BN, bool DO_RELU, bool OUT_FLEX, bool V_TRANS>
__global__ __launch_bounds__(256)
void gemm_bt(const bf16* __restrict__ A, const bf16* __restrict__ BT,
             const float* __restrict__ bias,
             void* __restrict__ Cv, int N, int K, int ldc,
             bf16* __restrict__ C2, int ldc2, int nsplit, int nvalid,
             int gy, bf16* __restrict__ vt_out,
             const int* __restrict__ flag) {
  constexpr int BK = 64;
  constexpr int TRM = BM / 32;                 // per-wave M fragments (4 / 2)
  constexpr int TCN = BN / 32;                 // per-wave N fragments (4)
  constexpr int ACH = (BM * BK) / (256 * 8);   // 4 / 2
  constexpr int BCH = (BN * BK) / (256 * 8);   // 4
  static_assert(!V_TRANS || BM == 128, "V_TRANS path assumes BM=128");
  __shared__ __align__(16) char smem_raw[(BM * BK + BN * BK) * 2];
  bf16* As = (bf16*)smem_raw;
  bf16* Bs = As + BM * BK;
  const int tid = threadIdx.x;
  const int wave = tid >> 6, lane = tid & 63;
  const int quad = lane >> 4, lo = lane & 15;
  const int wm = wave >> 1, wn = wave & 1;

  int m0, n0;
  if (gy == 0) {             // plain 2-D grid
    m0 = blockIdx.x * BM;
    n0 = blockIdx.y * BN;
  } else {                   // XCD-chunk + supertile swizzle (1-D grid)
    const int nwg = gridDim.x;
    const int bid = blockIdx.x;
    const int sid = (bid & 7) * (nwg >> 3) + (bid >> 3);
    const int P = gy << 3;
    const int g = sid / P, r2 = sid - g * P;
    m0 = (g * 8 + (r2 & 7)) * BM;
    n0 = (r2 >> 3) * BN;
  }

  floatx4 acc[TRM][TCN];
#pragma unroll
  for (int i = 0; i < TRM; i++)
#pragma unroll
    for (int j = 0; j < TCN; j++) acc[i][j] = floatx4{0.f, 0.f, 0.f, 0.f};

  for (int kb = 0; kb < K; kb += BK) {
#pragma unroll
    for (int u = 0; u < ACH; u++) {
      const int c = u * 256 + tid;
      const int row = c >> 3, col = c & 7;
      const int gcol = col ^ (row & 7);
      const bf16* gp = A + (size_t)(m0 + row) * K + kb + gcol * 8;
      __builtin_amdgcn_global_load_lds((gas1p)gp, (las3p)(As + c * 8), 16, 0, 0);
    }
#pragma unroll
    for (int u = 0; u < BCH; u++) {
      const int c = u * 256 + tid;
      const int row = c >> 3, col = c & 7;
      const int gcol = col ^ (row & 7);
      const bf16* gp = BT + (size_t)(n0 + row) * K + kb + gcol * 8;
      __builtin_amdgcn_global_load_lds((gas1p)gp, (las3p)(Bs + c * 8), 16, 0, 0);
    }
    __syncthreads();
#pragma unroll
    for (int kk = 0; kk < 2; kk++) {
      bf16x8 af[TRM], bfr[TCN];
#pragma unroll
      for (int tr = 0; tr < TRM; tr++) {
        const int row = wm * (BM / 2) + tr * 16 + lo;
        const int cc = (kk * 4 + quad) ^ (lo & 7);
        af[tr] = *reinterpret_cast<const bf16x8*>(As + row * BK + cc * 8);
      }
#pragma unroll
      for (int tc = 0; tc < TCN; tc++) {
        const int row = wn * (BN / 2) + tc * 16 + lo;
        const int cc = (kk * 4 + quad) ^ (lo & 7);
        bfr[tc] = *reinterpret_cast<const bf16x8*>(Bs + row * BK + cc * 8);
      }
#pragma unroll
      for (int tr = 0; tr < TRM; tr++)
#pragma unroll
        for (int tc = 0; tc < TCN; tc++)
          acc[tr][tc] = mfma_bf16(af[tr], bfr[tc], acc[tr][tc]);
    }
    __syncthreads();
  }

  // ---- V-transpose epilogue (block-uniform branch; BM=128 only) ----
  if constexpr (V_TRANS) {
    if (n0 >= 2048 && n0 < 3072) {
      const int h = ((n0 - 2048) >> 6) + wn;
      const int b = m0 >> 10;
      const int ibase = (m0 & 1023) + wm * 64;
      bf16* L = ((bf16*)smem_raw) + wave * 4096;    // private 64x64 slab (8 KB)
#pragma unroll
      for (int tc = 0; tc < TCN; tc++) {
        const int d = tc * 16 + lo;
        const float bval = bias[n0 + wn * 64 + d];
#pragma unroll
        for (int tr = 0; tr < TRM; tr++) {
          const int iin = tr * 16 + quad * 4;
          bf16x4 p;
#pragma unroll
          for (int rr = 0; rr < 4; rr++) p[rr] = (bf16)(acc[tr][tc][rr] + bval);
          *reinterpret_cast<bf16x4*>(L + d * 64 + (iin ^ ((d & 7) << 3))) = p;
        }
      }
      asm volatile("s_waitcnt lgkmcnt(0)" ::: "memory");
      bf16* dst = vt_out + (size_t)(b * 16 + h) * (HDIM * SEQ) + ibase;
#pragma unroll
      for (int w8 = 0; w8 < 8; w8++) {
        const int dp = w8 * 8 + (lane >> 3);
        const int ip = (lane & 7) * 8;
        const bf16x8 v = *reinterpret_cast<const bf16x8*>(
            L + dp * 64 + (ip ^ ((dp & 7) << 3)));
        *reinterpret_cast<bf16x8*>(dst + (size_t)dp * SEQ + ip) = v;
      }
      return;
    }
  }

  const int isbf = OUT_FLEX ? *flag : 1;
#pragma unroll
  for (int tc = 0; tc < TCN; tc++) {
    const int col = n0 + wn * (BN / 2) + tc * 16 + lo;
    const float bval = bias[col];
    if (col < nsplit) {
#pragma unroll
      for (int tr = 0; tr < TRM; tr++) {
        const int rbase = m0 + wm * (BM / 2) + tr * 16 + quad * 4;
#pragma unroll
        for (int rr = 0; rr < 4; rr++) {
          float v = acc[tr][tc][rr] + bval;
          if (DO_RELU) v = fmaxf(v, 0.f);
          const size_t idx = (size_t)(rbase + rr) * ldc + col;
          if (!OUT_FLEX || isbf) ((bf16*)Cv)[idx] = (bf16)v;
          else                   ((float*)Cv)[idx] = v;
        }
      }
    } else if (col < nvalid) {
#pragma unroll
      for (int tr = 0; tr < TRM; tr++) {
        const int rbase = m0 + wm * (BM / 2) + tr * 16 + quad * 4;
#pragma unroll
        for (int rr = 0; rr < 4; rr++) {
          float v = acc[tr][tc][rr] + bval;
          if (DO_RELU) v = fmaxf(v, 0.f);
          C2[(size_t)(rbase + rr) * ldc2 + (col - nsplit)] = (bf16)v;
        }
      }
    }
  }
}

// ---------------- flash attention: S^T formulation + LDS staging ----------------
// i-block 64 rows, grid 2048 (R4 win); T14 async reg-staging (R9).
__global__ __launch_bounds__(256)
void attn_kernel(const bf16* __restrict__ QKV, const bf16* __restrict__ Vt,
                 bf16* __restrict__ Cc) {
  __shared__ bf16 Ks[64 * 64];
  __shared__ bf16 Vs[64 * 64];
  const int bid = blockIdx.x;
  const int xcd = bid & 7, g = bid >> 3;
  const int ib = g & 15, bh = (g >> 4) * 8 + xcd;
  const int b = bh >> 4, h = bh & 15;
  const int i0 = ib * 64;
  const int tid = threadIdx.x, wave = tid >> 6, lane = tid & 63;
  const int quad = lane >> 4, lo = lane & 15;
  const int iw = i0 + wave * 16;
  const bf16* qptr = QKV + (size_t)b * SEQ * QKV_LD + h * HDIM;
  const bf16* kptr = QKV + (size_t)b * SEQ * QKV_LD + 1024 + h * HDIM;
  const bf16* vptr = Vt + (size_t)bh * HDIM * SEQ;

  // staging decomposition (loop-invariant)
  const int c0 = tid, c1 = 256 + tid;
  const int row0 = c0 >> 3, gcol0 = (c0 & 7) ^ (row0 & 7);
  const int row1 = c1 >> 3, gcol1 = (c1 & 7) ^ (row1 & 7);

  bf16x8 qf[2];
#pragma unroll
  for (int kf = 0; kf < 2; kf++)
    qf[kf] = *reinterpret_cast<const bf16x8*>(
        qptr + (size_t)(iw + lo) * QKV_LD + kf * 32 + quad * 8);

  floatx4 oacc[4];
  float lrow = 0.f;
#pragma unroll
  for (int dt = 0; dt < 4; dt++) oacc[dt] = floatx4{0.f, 0.f, 0.f, 0.f};

  // prologue: load tile 0 into registers
  bf16x8 kreg0 = *reinterpret_cast<const bf16x8*>(
      kptr + (size_t)row0 * QKV_LD + gcol0 * 8);
  bf16x8 kreg1 = *reinterpret_cast<const bf16x8*>(
      kptr + (size_t)row1 * QKV_LD + gcol1 * 8);
  bf16x8 vreg0 = *reinterpret_cast<const bf16x8*>(
      vptr + (size_t)row0 * SEQ + gcol0 * 8);
  bf16x8 vreg1 = *reinterpret_cast<const bf16x8*>(
      vptr + (size_t)row1 * SEQ + gcol1 * 8);

  for (int jb = 0; jb < SEQ / 64; jb++) {
    const int j0 = jb * 64;
    __syncthreads();   // all waves done reading previous tile
    *reinterpret_cast<bf16x8*>(Ks + c0 * 8) = kreg0;
    *reinterpret_cast<bf16x8*>(Ks + c1 * 8) = kreg1;
    *reinterpret_cast<bf16x8*>(Vs + c0 * 8) = vreg0;
    *reinterpret_cast<bf16x8*>(Vs + c1 * 8) = vreg1;
    __syncthreads();   // tile jb visible in LDS
    if (jb + 1 < SEQ / 64) {
      const int jn = j0 + 64;   // loads overlap the compute phase below
      kreg0 = *reinterpret_cast<const bf16x8*>(
          kptr + (size_t)(jn + row0) * QKV_LD + gcol0 * 8);
      kreg1 = *reinterpret_cast<const bf16x8*>(
          kptr + (size_t)(jn + row1) * QKV_LD + gcol1 * 8);
      vreg0 = *reinterpret_cast<const bf16x8*>(
          vptr + (size_t)row0 * SEQ + jn + gcol0 * 8);
      vreg1 = *reinterpret_cast<const bf16x8*>(
          vptr + (size_t)row1 * SEQ + jn + gcol1 * 8);
    }

    floatx4 sacc[4];
#pragma unroll
    for (int mt = 0; mt < 4; mt++) sacc[mt] = floatx4{0.f, 0.f, 0.f, 0.f};
    __builtin_amdgcn_s_setprio(1);
#pragma unroll
    for (int mt = 0; mt < 4; mt++) {
      const int r = mt * 16 + lo;
      const int cc0 = quad ^ (lo & 7);
      const int cc1 = (4 + quad) ^ (lo & 7);
      const bf16x8 k0 = *reinterpret_cast<const bf16x8*>(Ks + r * 64 + cc0 * 8);
      const bf16x8 k1 = *reinterpret_cast<const bf16x8*>(Ks + r * 64 + cc1 * 8);
      sacc[mt] = mfma_bf16(k0, qf[0], sacc[mt]);
      sacc[mt] = mfma_bf16(k1, qf[1], sacc[mt]);
    }
    __builtin_amdgcn_s_setprio(0);

    if (j0 == i0) {
      const int ig = iw + lo;
#pragma unroll
      for (int mt = 0; mt < 4; mt++)
#pragma unroll
        for (int r = 0; r < 4; r++)
          if (j0 + mt * 16 + quad * 4 + r == ig) sacc[mt][r] = -1e30f;
    }

    bf16x4 pfrag[4];
    {
      float s0 = 0.f, s1 = 0.f;
#pragma unroll
      for (int mt = 0; mt < 4; mt++) {
        bf16x4 pk;
#pragma unroll
        for (int r = 0; r < 4; r++) {
          const float p = fast_exp2(sacc[mt][r]);  // LOG2E folded into q scale
          if (mt & 1) s1 += p; else s0 += p;
          pk[r] = (bf16)p;
        }
        pfrag[mt] = pk;
      }
      float s = s0 + s1;
      s += __shfl_xor(s, 16);
      s += __shfl_xor(s, 32);
      lrow += s;
    }

    __builtin_amdgcn_s_setprio(1);
#pragma unroll
    for (int dt = 0; dt < 4; dt++) {
      const int r = dt * 16 + lo;
#pragma unroll
      for (int kt = 0; kt < 4; kt++) {
        const int gch = kt * 2 + (quad >> 1);
        const int cc = gch ^ (lo & 7);
        const bf16x4 vf = *reinterpret_cast<const bf16x4*>(
            Vs + r * 64 + cc * 8 + (quad & 1) * 4);
        oacc[dt] = mfma16(vf, pfrag[kt], oacc[dt]);
      }
    }
    __builtin_amdgcn_s_setprio(0);
  }

  {
    const int ig = iw + lo;
    const float inv = 1.0f / lrow;
    bf16* cb = Cc + ((size_t)b * SEQ + ig) * FF_IN + h * HDIM;
#pragma unroll
    for (int dt = 0; dt < 4; dt++) {
      bf16x4 o;
#pragma unroll
      for (int r = 0; r < 4; r++) o[r] = (bf16)(oacc[dt][r] * inv);
      *reinterpret_cast<bf16x4*>(cb + dt * 16 + quad * 4) = o;
    }
  }
}

// ---------------- launch ----------------
extern "C" void kernel_launch(void* const* d_in, const int* in_sizes, int n_in,
                              void* d_out, int out_size, void* d_ws, size_t ws_size,
                              hipStream_t stream) {
  (void)in_sizes; (void)n_in; (void)out_size; (void)ws_size;
  const void* x   = d_in[0];
  const void* Wq  = d_in[1];
  const void* bq  = d_in[2];
  const void* Wk  = d_in[3];
  const void* bk  = d_in[4];
  const void* Wv  = d_in[5];
  const void* bv  = d_in[6];
  const void* Win = d_in[7];
  const void* bin = d_in[8];
  const void* W1  = d_in[9];
  const void* b1  = d_in[10];
  const void* W2  = d_in[11];
  const void* b2  = d_in[12];

  size_t off = 0;
  char* wsb = (char*)d_ws;
  auto alloc = [&](size_t bytes) {
    void* p = (void*)(wsb + off);
    off += (bytes + 255) & ~(size_t)255;
    return p;
  };
  int*   flag  = (int*)alloc(4);
  bf16*  xbf   = (bf16*)alloc((size_t)ROWS * D_MODEL * 2);
  bf16*  WqkvT = (bf16*)alloc((size_t)3200 * 1024 * 2);  // q|k|v|in rows + pad
  bf16*  W1T   = (bf16*)alloc((size_t)FF_HID * FF_IN * 2);
  bf16*  W2T   = (bf16*)alloc((size_t)D_MODEL * FF_HID * 2);
  float* biasf = (float*)alloc(6208 * 4);   // qkv | bin | b1 | b2
  bf16*  qkv   = (bf16*)alloc((size_t)ROWS * QKV_LD * 2);
  bf16*  vtb   = (bf16*)alloc((size_t)ROWS * D_MODEL * 2);
  bf16*  cbuf  = (bf16*)alloc((size_t)ROWS * FF_IN * 2);
  bf16*  hbuf  = (bf16*)alloc((size_t)ROWS * FF_HID * 2);
  float* b1f   = biasf + 3136;
  float* b2f   = biasf + 5184;

  const dim3 blk(256);

  TransJobs J;
  J.src[0] = Wq;  J.dst[0] = WqkvT;                        J.R[0] = 1024; J.C[0] = 1024; J.scale[0] = 0.125f * LOG2E;
  J.src[1] = Wk;  J.dst[1] = WqkvT + (size_t)1024 * 1024;  J.R[1] = 1024; J.C[1] = 1024; J.scale[1] = 1.0f;
  J.src[2] = Wv;  J.dst[2] = WqkvT + (size_t)2048 * 1024;  J.R[2] = 1024; J.C[2] = 1024; J.scale[2] = 1.0f;
  J.src[3] = Win; J.dst[3] = WqkvT + (size_t)3072 * 1024;  J.R[3] = 1024; J.C[3] = 64;   J.scale[3] = 1.0f;
  J.src[4] = W1;  J.dst[4] = W1T;                          J.R[4] = 1088; J.C[4] = 2048; J.scale[4] = 1.0f;
  J.src[5] = W2;  J.dst[5] = W2T;                          J.R[5] = 2048; J.C[5] = 1024; J.scale[5] = 1.0f;
  int base = 0;
  for (int j = 0; j < 6; j++) {
    J.tiles_x[j] = J.C[j] / 32;
    J.tile_base[j] = base;
    base += (J.R[j] / 32) * (J.C[j] / 32);
  }
  J.tile_base[6] = base;

  // fused prep: x->bf16 (4096) | biases (25) | transposes (base); self-detects
  prep_all_kernel<<<dim3(NBX + NBB + base), blk, 0, stream>>>(
      x, xbf, bq, bk, bv, bin, b1, b2, biasf, J, flag);

  // fused QKV + in-proj projection (verified 2-barrier 128^2 + swizzle,
  // ~81 us): cols [0,2048) -> qkv (q|k), [2048,3072) -> vtb TRANSPOSED,
  // [3072,3136) -> cbuf tail, rest dropped. 1-D grid 1600, gy=25.
  gemm_bt<128, 128, false, false, true><<<dim3(1600), blk, 0, stream>>>(
      xbf, WqkvT, biasf, qkv, 3200, 1024, QKV_LD,
      cbuf + 1024, FF_IN, 3072, 3136, 25, vtb, nullptr);

  attn_kernel<<<dim3(2048), blk, 0, stream>>>(qkv, vtb, cbuf);

  // FFN: FF1 128x128 (1024 blocks, 4/CU). FF2 64x128 (1024 blocks, 4-6/CU;
  // BN kept at 128 so A-traffic is unchanged vs BM=128 — only the
  // L2-resident 4 MB W2T is re-read more).
  gemm_bt<128, 128, true, false, false><<<dim3(64, 16), blk, 0, stream>>>(
      cbuf, W1T, b1f, hbuf, FF_HID, FF_IN, FF_HID,
      nullptr, 0, FF_HID, FF_HID, 0, nullptr, nullptr);
  gemm_bt<64, 128, false, true, false><<<dim3(128, 8), blk, 0, stream>>>(
      hbuf, W2T, b2f, d_out, D_MODEL, FF_HID, D_MODEL,
      nullptr, 0, D_MODEL, D_MODEL, 0, nullptr, flag);
}

// Round 12
// 371.631 us; speedup vs baseline: 1.0349x; 1.0101x over previous
//
#include <hip/hip_runtime.h>

typedef __bf16 bf16;
typedef __attribute__((ext_vector_type(8))) __bf16 bf16x8;
typedef __attribute__((ext_vector_type(4))) __bf16 bf16x4;
typedef __attribute__((ext_vector_type(4))) short short4_t;
typedef __attribute__((ext_vector_type(4))) float floatx4;

typedef const void __attribute__((address_space(1)))* gas1p;
typedef void __attribute__((address_space(3)))* las3p;

#define LOG2E 1.44269504088896340736f

static constexpr int D_MODEL = 1024;
static constexpr int N_HEADS = 16;
static constexpr int HDIM    = 64;
static constexpr int BSZ     = 8;
static constexpr int SEQ     = 1024;
static constexpr int ROWS    = BSZ * SEQ;   // 8192
static constexpr int FF_IN   = 1088;        // 17*64
static constexpr int FF_HID  = 2048;
static constexpr int QKV_LD  = 3072;        // q|k|v row stride in qkv buffer

__device__ __forceinline__ floatx4 mfma_bf16(bf16x8 a, bf16x8 b, floatx4 c) {
  return __builtin_amdgcn_mfma_f32_16x16x32_bf16(a, b, c, 0, 0, 0);
}

__device__ __forceinline__ floatx4 mfma16(bf16x4 a, bf16x4 b, floatx4 c) {
#if __has_builtin(__builtin_amdgcn_mfma_f32_16x16x16_bf16)
  return __builtin_amdgcn_mfma_f32_16x16x16_bf16(a, b, c, 0, 0, 0);
#else
  return __builtin_amdgcn_mfma_f32_16x16x16bf16_1k(
      __builtin_bit_cast(short4_t, a), __builtin_bit_cast(short4_t, b), c, 0, 0, 0);
#endif
}

__device__ __forceinline__ float fast_exp2(float x) {
#if __has_builtin(__builtin_amdgcn_exp2f)
  return __builtin_amdgcn_exp2f(x);   // raw v_exp_f32, no libm guards
#else
  return exp2f(x);
#endif
}

__device__ __forceinline__ float flex_load(const void* src, size_t idx, int isbf) {
  return isbf ? (float)((const bf16*)src)[idx] : ((const float*)src)[idx];
}

// ---------------- fused prep: x->bf16 | biases | weight transposes ----------------
struct TransJobs {
  const void* src[6];
  bf16* dst[6];
  int R[6], C[6];
  int tiles_x[6];
  int tile_base[7];
  float scale[6];
};

static constexpr int NBX = (ROWS * D_MODEL) / 2048;   // 4096 blocks, 8 elem/thr
static constexpr int NBB = 25;                         // bias blocks

__global__ __launch_bounds__(256)
void prep_all_kernel(const void* __restrict__ xsrc, bf16* __restrict__ xdst,
                     const void* bq, const void* bk, const void* bv,
                     const void* bin, const void* b1, const void* b2,
                     float* __restrict__ biasf, TransJobs J,
                     int* __restrict__ flagOut) {
  __shared__ float tile[32][33];
  __shared__ int cnt;
  // ---- local dtype detect (1 sample/thread, same indices every block) ----
  if (threadIdx.x == 0) cnt = 0;
  __syncthreads();
  {
    const unsigned v = ((const unsigned*)xsrc)[(size_t)threadIdx.x * 997 + 13];
    const unsigned bb = (v >> 8) & 0x7F;
    if (bb >= 0x3B && bb <= 0x41) atomicAdd(&cnt, 1);
  }
  __syncthreads();
  const int isbf = (cnt > 128) ? 1 : 0;
  const int bid = blockIdx.x;
  if (bid == NBX && threadIdx.x == 0) *flagOut = isbf;

  if (bid < NBX) {                       // ---- x -> bf16 ----
    const size_t i = ((size_t)bid * 256 + threadIdx.x) * 8;
    bf16x8 o;
    if (isbf) {
      o = *reinterpret_cast<const bf16x8*>((const bf16*)xsrc + i);
    } else {
      const float4 f0 = *reinterpret_cast<const float4*>((const float*)xsrc + i);
      const float4 f1 = *reinterpret_cast<const float4*>((const float*)xsrc + i + 4);
      o[0] = (bf16)f0.x; o[1] = (bf16)f0.y; o[2] = (bf16)f0.z; o[3] = (bf16)f0.w;
      o[4] = (bf16)f1.x; o[5] = (bf16)f1.y; o[6] = (bf16)f1.z; o[7] = (bf16)f1.w;
    }
    *reinterpret_cast<bf16x8*>(xdst + i) = o;
    return;
  }
  if (bid < NBX + NBB) {                 // ---- biases ----
    const int i = (bid - NBX) * 256 + threadIdx.x;
    if (i < 1024)      biasf[i] = flex_load(bq, i, isbf) * (0.125f * LOG2E);
    else if (i < 2048) biasf[i] = flex_load(bk, i - 1024, isbf);
    else if (i < 3072) biasf[i] = flex_load(bv, i - 2048, isbf);
    else if (i < 3136) biasf[i] = flex_load(bin, i - 3072, isbf);
    else if (i < 5184) biasf[i] = flex_load(b1, i - 3136, isbf);
    else if (i < 6208) biasf[i] = flex_load(b2, i - 5184, isbf);
    return;
  }
  // ---- weight transposes ----
  const int tb = bid - (NBX + NBB);
  int j = 0;
#pragma unroll
  for (int t = 1; t < 6; t++) j += (tb >= J.tile_base[t]) ? 1 : 0;
  const int t = tb - J.tile_base[j];
  const int c0 = (t % J.tiles_x[j]) * 32, r0 = (t / J.tiles_x[j]) * 32;
  const void* src = J.src[j];
  bf16* dst = J.dst[j];
  const int R = J.R[j], C = J.C[j];
  const float scale = J.scale[j];
  const int tx = threadIdx.x & 31, ty = threadIdx.x >> 5;
  for (int i = ty; i < 32; i += 8)
    tile[i][tx] = flex_load(src, (size_t)(r0 + i) * C + (c0 + tx), isbf);
  __syncthreads();
  for (int i = ty; i < 32; i += 8)
    dst[(size_t)(c0 + i) * R + (r0 + tx)] = (bf16)(tile[tx][i] * scale);
}

// ---------------- GEMM: C[M,N] = A[M,K] @ BT[N,K]^T + bias ----------------
// Verified 2-barrier structure (BK=64, 256 thr, XOR-swizzled global_load_lds
// staging). BM templated: FF2 uses BM=64 (4-6 blocks/CU). gy>0 -> XCD-chunk
// supertile swizzle (verified -22 us on QKV, rounds 6-9).
// Round-12: swizzle re-applied to FF1/FF2 now that per-XCD A-chunks fit L2
// (FF1: 8x128x1088x2 = 2.2 MB; FF2 at BM=64: 8x64x2048x2 = 2.0 MB; R6's
// regression is explained by FF2-at-BM=128's 4.2 MB chunk thrashing the
// 4 MB per-XCD L2 — that configuration no longer exists).
template <int BM, int BN, bool DO_RELU, bool OUT_FLEX, bool V_TRANS>
__global__ __launch_bounds__(256)
void gemm_bt(const bf16* __restrict__ A, const bf16* __restrict__ BT,
             const float* __restrict__ bias,
             void* __restrict__ Cv, int N, int K, int ldc,
             bf16* __restrict__ C2, int ldc2, int nsplit, int nvalid,
             int gy, bf16* __restrict__ vt_out,
             const int* __restrict__ flag) {
  constexpr int BK = 64;
  constexpr int TRM = BM / 32;                 // per-wave M fragments (4 / 2)
  constexpr int TCN = BN / 32;                 // per-wave N fragments (4)
  constexpr int ACH = (BM * BK) / (256 * 8);   // 4 / 2
  constexpr int BCH = (BN * BK) / (256 * 8);   // 4
  static_assert(!V_TRANS || BM == 128, "V_TRANS path assumes BM=128");
  __shared__ __align__(16) char smem_raw[(BM * BK + BN * BK) * 2];
  bf16* As = (bf16*)smem_raw;
  bf16* Bs = As + BM * BK;
  const int tid = threadIdx.x;
  const int wave = tid >> 6, lane = tid & 63;
  const int quad = lane >> 4, lo = lane & 15;
  const int wm = wave >> 1, wn = wave & 1;

  int m0, n0;
  if (gy == 0) {             // plain 2-D grid
    m0 = blockIdx.x * BM;
    n0 = blockIdx.y * BN;
  } else {                   // XCD-chunk + supertile swizzle (1-D grid)
    const int nwg = gridDim.x;
    const int bid = blockIdx.x;
    const int sid = (bid & 7) * (nwg >> 3) + (bid >> 3);
    const int P = gy << 3;
    const int g = sid / P, r2 = sid - g * P;
    m0 = (g * 8 + (r2 & 7)) * BM;
    n0 = (r2 >> 3) * BN;
  }

  floatx4 acc[TRM][TCN];
#pragma unroll
  for (int i = 0; i < TRM; i++)
#pragma unroll
    for (int j = 0; j < TCN; j++) acc[i][j] = floatx4{0.f, 0.f, 0.f, 0.f};

  for (int kb = 0; kb < K; kb += BK) {
#pragma unroll
    for (int u = 0; u < ACH; u++) {
      const int c = u * 256 + tid;
      const int row = c >> 3, col = c & 7;
      const int gcol = col ^ (row & 7);
      const bf16* gp = A + (size_t)(m0 + row) * K + kb + gcol * 8;
      __builtin_amdgcn_global_load_lds((gas1p)gp, (las3p)(As + c * 8), 16, 0, 0);
    }
#pragma unroll
    for (int u = 0; u < BCH; u++) {
      const int c = u * 256 + tid;
      const int row = c >> 3, col = c & 7;
      const int gcol = col ^ (row & 7);
      const bf16* gp = BT + (size_t)(n0 + row) * K + kb + gcol * 8;
      __builtin_amdgcn_global_load_lds((gas1p)gp, (las3p)(Bs + c * 8), 16, 0, 0);
    }
    __syncthreads();
#pragma unroll
    for (int kk = 0; kk < 2; kk++) {
      bf16x8 af[TRM], bfr[TCN];
#pragma unroll
      for (int tr = 0; tr < TRM; tr++) {
        const int row = wm * (BM / 2) + tr * 16 + lo;
        const int cc = (kk * 4 + quad) ^ (lo & 7);
        af[tr] = *reinterpret_cast<const bf16x8*>(As + row * BK + cc * 8);
      }
#pragma unroll
      for (int tc = 0; tc < TCN; tc++) {
        const int row = wn * (BN / 2) + tc * 16 + lo;
        const int cc = (kk * 4 + quad) ^ (lo & 7);
        bfr[tc] = *reinterpret_cast<const bf16x8*>(Bs + row * BK + cc * 8);
      }
#pragma unroll
      for (int tr = 0; tr < TRM; tr++)
#pragma unroll
        for (int tc = 0; tc < TCN; tc++)
          acc[tr][tc] = mfma_bf16(af[tr], bfr[tc], acc[tr][tc]);
    }
    __syncthreads();
  }

  // ---- V-transpose epilogue (block-uniform branch; BM=128 only) ----
  if constexpr (V_TRANS) {
    if (n0 >= 2048 && n0 < 3072) {
      const int h = ((n0 - 2048) >> 6) + wn;
      const int b = m0 >> 10;
      const int ibase = (m0 & 1023) + wm * 64;
      bf16* L = ((bf16*)smem_raw) + wave * 4096;    // private 64x64 slab (8 KB)
#pragma unroll
      for (int tc = 0; tc < TCN; tc++) {
        const int d = tc * 16 + lo;
        const float bval = bias[n0 + wn * 64 + d];
#pragma unroll
        for (int tr = 0; tr < TRM; tr++) {
          const int iin = tr * 16 + quad * 4;
          bf16x4 p;
#pragma unroll
          for (int rr = 0; rr < 4; rr++) p[rr] = (bf16)(acc[tr][tc][rr] + bval);
          *reinterpret_cast<bf16x4*>(L + d * 64 + (iin ^ ((d & 7) << 3))) = p;
        }
      }
      asm volatile("s_waitcnt lgkmcnt(0)" ::: "memory");
      bf16* dst = vt_out + (size_t)(b * 16 + h) * (HDIM * SEQ) + ibase;
#pragma unroll
      for (int w8 = 0; w8 < 8; w8++) {
        const int dp = w8 * 8 + (lane >> 3);
        const int ip = (lane & 7) * 8;
        const bf16x8 v = *reinterpret_cast<const bf16x8*>(
            L + dp * 64 + (ip ^ ((dp & 7) << 3)));
        *reinterpret_cast<bf16x8*>(dst + (size_t)dp * SEQ + ip) = v;
      }
      return;
    }
  }

  const int isbf = OUT_FLEX ? *flag : 1;
#pragma unroll
  for (int tc = 0; tc < TCN; tc++) {
    const int col = n0 + wn * (BN / 2) + tc * 16 + lo;
    const float bval = bias[col];
    if (col < nsplit) {
#pragma unroll
      for (int tr = 0; tr < TRM; tr++) {
        const int rbase = m0 + wm * (BM / 2) + tr * 16 + quad * 4;
#pragma unroll
        for (int rr = 0; rr < 4; rr++) {
          float v = acc[tr][tc][rr] + bval;
          if (DO_RELU) v = fmaxf(v, 0.f);
          const size_t idx = (size_t)(rbase + rr) * ldc + col;
          if (!OUT_FLEX || isbf) ((bf16*)Cv)[idx] = (bf16)v;
          else                   ((float*)Cv)[idx] = v;
        }
      }
    } else if (col < nvalid) {
#pragma unroll
      for (int tr = 0; tr < TRM; tr++) {
        const int rbase = m0 + wm * (BM / 2) + tr * 16 + quad * 4;
#pragma unroll
        for (int rr = 0; rr < 4; rr++) {
          float v = acc[tr][tc][rr] + bval;
          if (DO_RELU) v = fmaxf(v, 0.f);
          C2[(size_t)(rbase + rr) * ldc2 + (col - nsplit)] = (bf16)v;
        }
      }
    }
  }
}

// ---------------- flash attention: S^T formulation + LDS staging ----------------
// i-block 64 rows, grid 2048 (R4 win); T14 async reg-staging (R9).
__global__ __launch_bounds__(256)
void attn_kernel(const bf16* __restrict__ QKV, const bf16* __restrict__ Vt,
                 bf16* __restrict__ Cc) {
  __shared__ bf16 Ks[64 * 64];
  __shared__ bf16 Vs[64 * 64];
  const int bid = blockIdx.x;
  const int xcd = bid & 7, g = bid >> 3;
  const int ib = g & 15, bh = (g >> 4) * 8 + xcd;
  const int b = bh >> 4, h = bh & 15;
  const int i0 = ib * 64;
  const int tid = threadIdx.x, wave = tid >> 6, lane = tid & 63;
  const int quad = lane >> 4, lo = lane & 15;
  const int iw = i0 + wave * 16;
  const bf16* qptr = QKV + (size_t)b * SEQ * QKV_LD + h * HDIM;
  const bf16* kptr = QKV + (size_t)b * SEQ * QKV_LD + 1024 + h * HDIM;
  const bf16* vptr = Vt + (size_t)bh * HDIM * SEQ;

  // staging decomposition (loop-invariant)
  const int c0 = tid, c1 = 256 + tid;
  const int row0 = c0 >> 3, gcol0 = (c0 & 7) ^ (row0 & 7);
  const int row1 = c1 >> 3, gcol1 = (c1 & 7) ^ (row1 & 7);

  bf16x8 qf[2];
#pragma unroll
  for (int kf = 0; kf < 2; kf++)
    qf[kf] = *reinterpret_cast<const bf16x8*>(
        qptr + (size_t)(iw + lo) * QKV_LD + kf * 32 + quad * 8);

  floatx4 oacc[4];
  float lrow = 0.f;
#pragma unroll
  for (int dt = 0; dt < 4; dt++) oacc[dt] = floatx4{0.f, 0.f, 0.f, 0.f};

  // prologue: load tile 0 into registers
  bf16x8 kreg0 = *reinterpret_cast<const bf16x8*>(
      kptr + (size_t)row0 * QKV_LD + gcol0 * 8);
  bf16x8 kreg1 = *reinterpret_cast<const bf16x8*>(
      kptr + (size_t)row1 * QKV_LD + gcol1 * 8);
  bf16x8 vreg0 = *reinterpret_cast<const bf16x8*>(
      vptr + (size_t)row0 * SEQ + gcol0 * 8);
  bf16x8 vreg1 = *reinterpret_cast<const bf16x8*>(
      vptr + (size_t)row1 * SEQ + gcol1 * 8);

  for (int jb = 0; jb < SEQ / 64; jb++) {
    const int j0 = jb * 64;
    __syncthreads();   // all waves done reading previous tile
    *reinterpret_cast<bf16x8*>(Ks + c0 * 8) = kreg0;
    *reinterpret_cast<bf16x8*>(Ks + c1 * 8) = kreg1;
    *reinterpret_cast<bf16x8*>(Vs + c0 * 8) = vreg0;
    *reinterpret_cast<bf16x8*>(Vs + c1 * 8) = vreg1;
    __syncthreads();   // tile jb visible in LDS
    if (jb + 1 < SEQ / 64) {
      const int jn = j0 + 64;   // loads overlap the compute phase below
      kreg0 = *reinterpret_cast<const bf16x8*>(
          kptr + (size_t)(jn + row0) * QKV_LD + gcol0 * 8);
      kreg1 = *reinterpret_cast<const bf16x8*>(
          kptr + (size_t)(jn + row1) * QKV_LD + gcol1 * 8);
      vreg0 = *reinterpret_cast<const bf16x8*>(
          vptr + (size_t)row0 * SEQ + jn + gcol0 * 8);
      vreg1 = *reinterpret_cast<const bf16x8*>(
          vptr + (size_t)row1 * SEQ + jn + gcol1 * 8);
    }

    floatx4 sacc[4];
#pragma unroll
    for (int mt = 0; mt < 4; mt++) sacc[mt] = floatx4{0.f, 0.f, 0.f, 0.f};
    __builtin_amdgcn_s_setprio(1);
#pragma unroll
    for (int mt = 0; mt < 4; mt++) {
      const int r = mt * 16 + lo;
      const int cc0 = quad ^ (lo & 7);
      const int cc1 = (4 + quad) ^ (lo & 7);
      const bf16x8 k0 = *reinterpret_cast<const bf16x8*>(Ks + r * 64 + cc0 * 8);
      const bf16x8 k1 = *reinterpret_cast<const bf16x8*>(Ks + r * 64 + cc1 * 8);
      sacc[mt] = mfma_bf16(k0, qf[0], sacc[mt]);
      sacc[mt] = mfma_bf16(k1, qf[1], sacc[mt]);
    }
    __builtin_amdgcn_s_setprio(0);

    if (j0 == i0) {
      const int ig = iw + lo;
#pragma unroll
      for (int mt = 0; mt < 4; mt++)
#pragma unroll
        for (int r = 0; r < 4; r++)
          if (j0 + mt * 16 + quad * 4 + r == ig) sacc[mt][r] = -1e30f;
    }

    bf16x4 pfrag[4];
    {
      float s0 = 0.f, s1 = 0.f;
#pragma unroll
      for (int mt = 0; mt < 4; mt++) {
        bf16x4 pk;
#pragma unroll
        for (int r = 0; r < 4; r++) {
          const float p = fast_exp2(sacc[mt][r]);  // LOG2E folded into q scale
          if (mt & 1) s1 += p; else s0 += p;
          pk[r] = (bf16)p;
        }
        pfrag[mt] = pk;
      }
      float s = s0 + s1;
      s += __shfl_xor(s, 16);
      s += __shfl_xor(s, 32);
      lrow += s;
    }

    __builtin_amdgcn_s_setprio(1);
#pragma unroll
    for (int dt = 0; dt < 4; dt++) {
      const int r = dt * 16 + lo;
#pragma unroll
      for (int kt = 0; kt < 4; kt++) {
        const int gch = kt * 2 + (quad >> 1);
        const int cc = gch ^ (lo & 7);
        const bf16x4 vf = *reinterpret_cast<const bf16x4*>(
            Vs + r * 64 + cc * 8 + (quad & 1) * 4);
        oacc[dt] = mfma16(vf, pfrag[kt], oacc[dt]);
      }
    }
    __builtin_amdgcn_s_setprio(0);
  }

  {
    const int ig = iw + lo;
    const float inv = 1.0f / lrow;
    bf16* cb = Cc + ((size_t)b * SEQ + ig) * FF_IN + h * HDIM;
#pragma unroll
    for (int dt = 0; dt < 4; dt++) {
      bf16x4 o;
#pragma unroll
      for (int r = 0; r < 4; r++) o[r] = (bf16)(oacc[dt][r] * inv);
      *reinterpret_cast<bf16x4*>(cb + dt * 16 + quad * 4) = o;
    }
  }
}

// ---------------- launch ----------------
extern "C" void kernel_launch(void* const* d_in, const int* in_sizes, int n_in,
                              void* d_out, int out_size, void* d_ws, size_t ws_size,
                              hipStream_t stream) {
  (void)in_sizes; (void)n_in; (void)out_size; (void)ws_size;
  const void* x   = d_in[0];
  const void* Wq  = d_in[1];
  const void* bq  = d_in[2];
  const void* Wk  = d_in[3];
  const void* bk  = d_in[4];
  const void* Wv  = d_in[5];
  const void* bv  = d_in[6];
  const void* Win = d_in[7];
  const void* bin = d_in[8];
  const void* W1  = d_in[9];
  const void* b1  = d_in[10];
  const void* W2  = d_in[11];
  const void* b2  = d_in[12];

  size_t off = 0;
  char* wsb = (char*)d_ws;
  auto alloc = [&](size_t bytes) {
    void* p = (void*)(wsb + off);
    off += (bytes + 255) & ~(size_t)255;
    return p;
  };
  int*   flag  = (int*)alloc(4);
  bf16*  xbf   = (bf16*)alloc((size_t)ROWS * D_MODEL * 2);
  bf16*  WqkvT = (bf16*)alloc((size_t)3200 * 1024 * 2);  // q|k|v|in rows + pad
  bf16*  W1T   = (bf16*)alloc((size_t)FF_HID * FF_IN * 2);
  bf16*  W2T   = (bf16*)alloc((size_t)D_MODEL * FF_HID * 2);
  float* biasf = (float*)alloc(6208 * 4);   // qkv | bin | b1 | b2
  bf16*  qkv   = (bf16*)alloc((size_t)ROWS * QKV_LD * 2);
  bf16*  vtb   = (bf16*)alloc((size_t)ROWS * D_MODEL * 2);
  bf16*  cbuf  = (bf16*)alloc((size_t)ROWS * FF_IN * 2);
  bf16*  hbuf  = (bf16*)alloc((size_t)ROWS * FF_HID * 2);
  float* b1f   = biasf + 3136;
  float* b2f   = biasf + 5184;

  const dim3 blk(256);

  TransJobs J;
  J.src[0] = Wq;  J.dst[0] = WqkvT;                        J.R[0] = 1024; J.C[0] = 1024; J.scale[0] = 0.125f * LOG2E;
  J.src[1] = Wk;  J.dst[1] = WqkvT + (size_t)1024 * 1024;  J.R[1] = 1024; J.C[1] = 1024; J.scale[1] = 1.0f;
  J.src[2] = Wv;  J.dst[2] = WqkvT + (size_t)2048 * 1024;  J.R[2] = 1024; J.C[2] = 1024; J.scale[2] = 1.0f;
  J.src[3] = Win; J.dst[3] = WqkvT + (size_t)3072 * 1024;  J.R[3] = 1024; J.C[3] = 64;   J.scale[3] = 1.0f;
  J.src[4] = W1;  J.dst[4] = W1T;                          J.R[4] = 1088; J.C[4] = 2048; J.scale[4] = 1.0f;
  J.src[5] = W2;  J.dst[5] = W2T;                          J.R[5] = 2048; J.C[5] = 1024; J.scale[5] = 1.0f;
  int base = 0;
  for (int j = 0; j < 6; j++) {
    J.tiles_x[j] = J.C[j] / 32;
    J.tile_base[j] = base;
    base += (J.R[j] / 32) * (J.C[j] / 32);
  }
  J.tile_base[6] = base;

  // fused prep: x->bf16 (4096) | biases (25) | transposes (base); self-detects
  prep_all_kernel<<<dim3(NBX + NBB + base), blk, 0, stream>>>(
      x, xbf, bq, bk, bv, bin, b1, b2, biasf, J, flag);

  // fused QKV + in-proj projection (verified 2-barrier 128^2 + swizzle,
  // ~82 us): cols [0,2048) -> qkv (q|k), [2048,3072) -> vtb TRANSPOSED,
  // [3072,3136) -> cbuf tail, rest dropped. 1-D grid 1600, gy=25.
  gemm_bt<128, 128, false, false, true><<<dim3(1600), blk, 0, stream>>>(
      xbf, WqkvT, biasf, qkv, 3200, 1024, QKV_LD,
      cbuf + 1024, FF_IN, 3072, 3136, 25, vtb, nullptr);

  attn_kernel<<<dim3(2048), blk, 0, stream>>>(qkv, vtb, cbuf);

  // FFN with XCD-chunk swizzle (per-XCD A-chunks now L2-resident):
  //  FF1: 1024 = 64 M x 16 N (gy=16), A-chunk 2.2 MB
  //  FF2: 1024 = 128 M x 8 N (gy=8, BM=64), A-chunk 2.0 MB
  gemm_bt<128, 128, true, false, false><<<dim3(1024), blk, 0, stream>>>(
      cbuf, W1T, b1f, hbuf, FF_HID, FF_IN, FF_HID,
      nullptr, 0, FF_HID, FF_HID, 16, nullptr, nullptr);
  gemm_bt<64, 128, false, true, false><<<dim3(1024), blk, 0, stream>>>(
      hbuf, W2T, b2f, d_out, D_MODEL, FF_HID, D_MODEL,
      nullptr, 0, D_MODEL, D_MODEL, 8, nullptr, flag);
}